// Round 11
// baseline (156.413 us; speedup 1.0000x reference)
//
#include <hip/hip_runtime.h>
#include <math.h>

#define S_LEN 1024
#define D_DIM 64
#define NBH   16

typedef unsigned short ushort_t;
typedef __attribute__((ext_vector_type(8))) short short8;   // 8 bf16 (4 VGPRs)
typedef __attribute__((ext_vector_type(4))) short short4v;  // 4 bf16 (8 B)
typedef __attribute__((ext_vector_type(4))) float f32x4;
typedef __attribute__((ext_vector_type(2))) float f32x2;

__device__ __forceinline__ ushort_t rne_bf16(float x) {
    unsigned u = __float_as_uint(x);
    return (ushort_t)((u + 0x7FFFu + ((u >> 16) & 1u)) >> 16);
}
__device__ __forceinline__ void split1(float x, ushort_t& h, ushort_t& l) {
    h = rne_bf16(x);
    float hf = __uint_as_float((unsigned)h << 16);
    l = rne_bf16(x - hf);
}

// ------------------------------ Prep ----------------------------------------
// blocks [0,256):   V transpose-split -> PV B-frag tiled layout
// blocks [256,512): mask bit-pack, thread-per-word
__global__ __launch_bounds__(256) void prep(
    const float* __restrict__ v, const int* __restrict__ mask,
    ushort_t* __restrict__ vhi, ushort_t* __restrict__ vlo,
    unsigned* __restrict__ mw)
{
    __shared__ float Ls[64][65];
    const int tid = threadIdx.x;
    const int bx = blockIdx.x;
    if (bx < 256) {
        const int tt = bx & 15, bh = bx >> 4;
        const float* vb = v + ((size_t)bh * S_LEN + tt * 64) * D_DIM;
        #pragma unroll
        for (int p = 0; p < 4; ++p) {
            int idx = p * 1024 + tid * 4;
            int r = idx >> 6, c = idx & 63;
            float4 x = *(const float4*)(vb + r * 64 + c);
            Ls[r][c] = x.x; Ls[r][c+1] = x.y; Ls[r][c+2] = x.z; Ls[r][c+3] = x.w;
        }
        __syncthreads();
        const int d = tid >> 2, c0 = (tid & 3) * 16;
        ushort_t hi[16], lo[16];
        #pragma unroll
        for (int j = 0; j < 16; ++j) split1(Ls[c0 + j][d], hi[j], lo[j]);
        const int tb0 = tt * 8 + (c0 >> 3);
        const size_t o0 = (((size_t)bh * 128 + tb0) * 64 + d) * 8;
        const size_t o1 = (((size_t)bh * 128 + tb0 + 1) * 64 + d) * 8;
        *(short8*)(vhi + o0) = *(short8*)(hi);
        *(short8*)(vhi + o1) = *(short8*)(hi + 8);
        *(short8*)(vlo + o0) = *(short8*)(lo);
        *(short8*)(vlo + o1) = *(short8*)(lo + 8);
    } else {
        const int gid = (bx - 256) * 256 + tid;    // 0..65535
        const int row = gid >> 5, wd = gid & 31;   // row = b*1024+s
        const int4* mp = (const int4*)(mask + (size_t)row * 1024 + wd * 32);
        unsigned bits = 0;
        #pragma unroll
        for (int p = 0; p < 8; ++p) {
            int4 qv = mp[p];
            bits |= (qv.x != 0 ? 1u : 0u) << (p * 4 + 0);
            bits |= (qv.y != 0 ? 1u : 0u) << (p * 4 + 1);
            bits |= (qv.z != 0 ? 1u : 0u) << (p * 4 + 2);
            bits |= (qv.w != 0 ? 1u : 0u) << (p * 4 + 3);
        }
        mw[(size_t)row * 32 + wd] = bits;
    }
}

// ---------- K1: dp = (1/8) Q.K^T, MFMA, in-kernel K split, LDS-transposed ----
// grid (4 t-strips, 64 s-tiles, 16 bh), block 256 = 4 waves.
// Wave w: tiles strip*16+w*4 .. +3 (64 cols). Stores via per-wave LDS
// transpose -> 4 coalesced float4 stores (256B runs).
__global__ __launch_bounds__(256) void qk_mfma(
    const float* __restrict__ q, const float* __restrict__ k,
    float* __restrict__ dp)
{
    __shared__ float Ls[4][16][68];       // 17.4 KB, per-wave private
    const int strip = blockIdx.x, st = blockIdx.y, bh = blockIdx.z;
    const int s0 = st * 16;
    const int tid = threadIdx.x;
    const int wave = tid >> 6, lane = tid & 63;
    const int m = lane & 15, quad = lane >> 4;

    // A fragments: Q rows s0+m, fp32 load + in-register split
    const float* qp = q + ((size_t)bh * S_LEN + s0 + m) * D_DIM + quad * 8;
    float qa[16];
    *(float4*)(qa + 0)  = *(const float4*)(qp + 0);
    *(float4*)(qa + 4)  = *(const float4*)(qp + 4);
    *(float4*)(qa + 8)  = *(const float4*)(qp + 32);
    *(float4*)(qa + 12) = *(const float4*)(qp + 36);
    short8 ahi0, alo0, ahi1, alo1;
    #pragma unroll
    for (int i = 0; i < 8; ++i) {
        ushort_t h, l;
        split1(qa[i], h, l);      ahi0[i] = (short)h; alo0[i] = (short)l;
        split1(qa[8 + i], h, l);  ahi1[i] = (short)h; alo1[i] = (short)l;
    }

    const int tile0 = strip * 16 + wave * 4;
    float* dpb = dp + ((size_t)bh * S_LEN + s0) * S_LEN;

    #pragma unroll
    for (int tt = 0; tt < 4; ++tt) {
        const int t0 = (tile0 + tt) * 16;
        // B fragments: K rows t0+m, fp32 load + split (K is L2-hot)
        const float* kp = k + ((size_t)bh * S_LEN + t0 + m) * D_DIM + quad * 8;
        float kb[16];
        *(float4*)(kb + 0)  = *(const float4*)(kp + 0);
        *(float4*)(kb + 4)  = *(const float4*)(kp + 4);
        *(float4*)(kb + 8)  = *(const float4*)(kp + 32);
        *(float4*)(kb + 12) = *(const float4*)(kp + 36);
        short8 bhi0, blo0, bhi1, blo1;
        #pragma unroll
        for (int i = 0; i < 8; ++i) {
            ushort_t h, l;
            split1(kb[i], h, l);      bhi0[i] = (short)h; blo0[i] = (short)l;
            split1(kb[8 + i], h, l);  bhi1[i] = (short)h; blo1[i] = (short)l;
        }
        f32x4 acc = {0.f, 0.f, 0.f, 0.f};
        acc = __builtin_amdgcn_mfma_f32_16x16x32_bf16(ahi0, bhi0, acc, 0, 0, 0);
        acc = __builtin_amdgcn_mfma_f32_16x16x32_bf16(ahi0, blo0, acc, 0, 0, 0);
        acc = __builtin_amdgcn_mfma_f32_16x16x32_bf16(alo0, bhi0, acc, 0, 0, 0);
        acc = __builtin_amdgcn_mfma_f32_16x16x32_bf16(ahi1, bhi1, acc, 0, 0, 0);
        acc = __builtin_amdgcn_mfma_f32_16x16x32_bf16(ahi1, blo1, acc, 0, 0, 0);
        acc = __builtin_amdgcn_mfma_f32_16x16x32_bf16(alo1, bhi1, acc, 0, 0, 0);
        #pragma unroll
        for (int r = 0; r < 4; ++r)
            Ls[wave][quad * 4 + r][tt * 16 + m] = acc[r] * 0.125f;
    }
    // wave-private transpose readback -> coalesced stores (no barrier needed)
    const int cb = strip * 256 + wave * 64;
    #pragma unroll
    for (int p = 0; p < 4; ++p) {
        const int row = p * 4 + (lane >> 4);
        const int f4  = lane & 15;
        float4 val = *(const float4*)&Ls[wave][row][f4 * 4];
        *(float4*)&dpb[(size_t)row * S_LEN + cb + f4 * 4] = val;
    }
}

// ---------- K2: conv+leaky+linear+mask+exp -> PV MFMA (direct global reads) --
// grid (64 s-tiles, 16 bh), block 512 = 8 waves. LDS ~40 KB.
// Conv: thread (rh=tid>>8, cg=tid&255) -> rows rh*8..+7, cols cg*4..+3,
// two passes of 4 rows, 6-row register window read straight from dp (L1/L2
// covers the 3x vertical reuse). P = unnormalized exp bf16 in LDS; PV wave w:
// d0=(w&3)*16, t-half w>>2; 1/rowsum folded into epilogue.
#define PSTR 1048   // pP row stride in ushorts (16B-aligned rows, 2-way banks)
__global__ __launch_bounds__(512) void conv_av(
    const float* __restrict__ dp, const unsigned* __restrict__ mw,
    const ushort_t* __restrict__ vhi, const ushort_t* __restrict__ vlo,
    const float* __restrict__ conv_w, const float* __restrict__ conv_b,
    const float* __restrict__ lin_w, const float* __restrict__ lin_b,
    float* __restrict__ out)
{
    __shared__ ushort_t pP[16 * PSTR];     // 33.5 KB
    __shared__ float oBuf[16][68];         // 4.4 KB
    __shared__ float lsPart[16][4];
    __shared__ unsigned mb[16][32];        // 2 KB

    const int st = blockIdx.x, bh = blockIdx.y;
    const int s0 = st * 16;
    const int b  = bh >> 3;
    const int tid = threadIdx.x;
    const int wave = tid >> 6, lane = tid & 63;
    const int m = lane & 15, quad = lane >> 4;

    // mask bits -> LDS (one word per thread)
    {
        const int row = tid >> 5, wd = tid & 31;
        mb[row][wd] = mw[((size_t)b * S_LEN + s0 + row) * 32 + wd];
    }

    float w[36];
    #pragma unroll
    for (int i = 0; i < 36; ++i) w[i] = conv_w[i];
    float cb[4], lw[4];
    #pragma unroll
    for (int f = 0; f < 4; ++f) { cb[f] = conv_b[f]; lw[f] = lin_w[f]; }
    const float lb = lin_b[0];

    const int rh = tid >> 8, cg = tid & 255, c0 = cg * 4;
    const float* dpb = dp + (size_t)bh * S_LEN * S_LEN;
    __syncthreads();   // mb visible

    #pragma unroll
    for (int pass = 0; pass < 2; ++pass) {
        const int obase = rh * 8 + pass * 4;        // first of 4 output rows
        // load 6-row window straight from global
        float rowv[6][6];
        #pragma unroll
        for (int jj = 0; jj < 6; ++jj) {
            const int ir = s0 + obase - 1 + jj;
            if (ir >= 0 && ir < S_LEN) {
                const float* rp = dpb + (size_t)ir * S_LEN + c0;
                f32x4 md = *(const f32x4*)rp;
                rowv[jj][0] = cg ? rp[-1] : 0.f;
                rowv[jj][1] = md.x; rowv[jj][2] = md.y;
                rowv[jj][3] = md.z; rowv[jj][4] = md.w;
                rowv[jj][5] = (cg < 255) ? rp[4] : 0.f;
            } else {
                #pragma unroll
                for (int i = 0; i < 6; ++i) rowv[jj][i] = 0.f;
            }
        }
        float ls[4];
        #pragma unroll
        for (int jo = 0; jo < 4; ++jo) {
            const int o = obase + jo;
            f32x2 pa = {lb, lb}, pb = {lb, lb};
            #pragma unroll
            for (int f = 0; f < 4; ++f) {
                f32x2 ca = {cb[f], cb[f]}, cbv = ca;
                #pragma unroll
                for (int dr = 0; dr < 3; ++dr) {
                    const float* vv = rowv[jo + dr];
                    #pragma unroll
                    for (int dc = 0; dc < 3; ++dc) {
                        const float wt = w[f * 9 + dr * 3 + dc];
                        f32x2 ia = {vv[dc],     vv[dc + 1]};
                        f32x2 ib = {vv[dc + 2], vv[dc + 3]};
                        ca  += wt * ia;
                        cbv += wt * ib;
                    }
                }
                f32x2 la  = {fmaxf(ca.x, 0.f)  + 0.01f * fminf(ca.x, 0.f),
                             fmaxf(ca.y, 0.f)  + 0.01f * fminf(ca.y, 0.f)};
                f32x2 lb2 = {fmaxf(cbv.x, 0.f) + 0.01f * fminf(cbv.x, 0.f),
                             fmaxf(cbv.y, 0.f) + 0.01f * fminf(cbv.y, 0.f)};
                pa += lw[f] * la;
                pb += lw[f] * lb2;
            }
            const unsigned word = mb[o][cg >> 3];
            const unsigned nib  = (word >> ((cg & 7) * 4)) & 0xFu;
            float pre[4] = {pa.x, pa.y, pb.x, pb.y};
            #pragma unroll
            for (int i = 0; i < 4; ++i)
                if (!((nib >> i) & 1u)) pre[i] = -1e30f;
            float pv[4];
            #pragma unroll
            for (int i = 0; i < 4; ++i) pv[i] = __expf(pre[i]);
            ls[jo] = (pv[0] + pv[1]) + (pv[2] + pv[3]);
            short4v hv = {(short)rne_bf16(pv[0]), (short)rne_bf16(pv[1]),
                          (short)rne_bf16(pv[2]), (short)rne_bf16(pv[3])};
            *(short4v*)&pP[o * PSTR + c0] = hv;
        }
        // row-sum partials: reduce 64 lanes, 4 waves per row-group
        #pragma unroll
        for (int jo = 0; jo < 4; ++jo) {
            float t = ls[jo];
            #pragma unroll
            for (int off = 1; off < 64; off <<= 1) t += __shfl_xor(t, off);
            if (lane == 0) lsPart[obase + jo][wave & 3] = t;
        }
    }
    __syncthreads();

    // ---- PV: wave w -> d0=(w&3)*16, t-chunks (w>>2)*16 .. +15 --------------
    const int d0 = (wave & 3) * 16;
    const int th = wave >> 2;
    f32x4 O = {0.f, 0.f, 0.f, 0.f};
    #pragma unroll 4
    for (int i = 0; i < 16; ++i) {
        const int c = th * 16 + i;
        short8 ph = *(const short8*)&pP[m * PSTR + c * 32 + quad * 8];
        const size_t vb = (((size_t)bh * 128 + c * 4 + quad) * 64 + d0 + m) * 8;
        short8 vh = *(const short8*)(vhi + vb);
        short8 vl = *(const short8*)(vlo + vb);
        O = __builtin_amdgcn_mfma_f32_16x16x32_bf16(ph, vh, O, 0, 0, 0);
        O = __builtin_amdgcn_mfma_f32_16x16x32_bf16(ph, vl, O, 0, 0, 0);
    }
    if (wave < 4) {
        #pragma unroll
        for (int r = 0; r < 4; ++r) oBuf[quad * 4 + r][d0 + m] = O[r];
    }
    __syncthreads();
    if (wave >= 4) {
        #pragma unroll
        for (int r = 0; r < 4; ++r) {
            const int br = quad * 4 + r;
            const float lsum = (lsPart[br][0] + lsPart[br][1]) +
                               (lsPart[br][2] + lsPart[br][3]);
            out[((size_t)bh * S_LEN + s0 + br) * D_DIM + d0 + m] =
                (O[r] + oBuf[br][d0 + m]) / lsum;
        }
    }
}

extern "C" void kernel_launch(void* const* d_in, const int* in_sizes, int n_in,
                              void* d_out, int out_size, void* d_ws, size_t ws_size,
                              hipStream_t stream) {
    const float* q      = (const float*)d_in[0];
    const float* k      = (const float*)d_in[1];
    const float* v      = (const float*)d_in[2];
    const int*   mask   = (const int*)d_in[3];
    const float* conv_w = (const float*)d_in[4];
    const float* conv_b = (const float*)d_in[5];
    const float* lin_w  = (const float*)d_in[6];
    const float* lin_b  = (const float*)d_in[7];
    float* out = (float*)d_out;

    char* wsb = (char*)d_ws;
    const size_t MB = 1024 * 1024;
    ushort_t* vhi = (ushort_t*)(wsb + 0 * MB);
    ushort_t* vlo = (ushort_t*)(wsb + 2 * MB);
    unsigned* mw  = (unsigned*)(wsb + 4 * MB);
    float*    dp  = (float*)(wsb + 16 * MB);      // 64 MiB

    prep<<<dim3(512), 256, 0, stream>>>(v, mask, vhi, vlo, mw);
    qk_mfma<<<dim3(4, 64, NBH), 256, 0, stream>>>(q, k, dp);
    conv_av<<<dim3(64, NBH), 512, 0, stream>>>(
        dp, mw, vhi, vlo, conv_w, conv_b, lin_w, lin_b, out);
}

// Round 12
// 136.177 us; speedup vs baseline: 1.1486x; 1.1486x over previous
//
#include <hip/hip_runtime.h>
#include <math.h>

#define S_LEN 1024
#define D_DIM 64
#define NBH   16

typedef unsigned short ushort_t;
typedef __attribute__((ext_vector_type(8))) short short8;   // 8 bf16 (4 VGPRs)
typedef __attribute__((ext_vector_type(4))) short short4v;  // 4 bf16 (8 B)
typedef __attribute__((ext_vector_type(4))) float f32x4;
typedef __attribute__((ext_vector_type(2))) float f32x2;

__device__ __forceinline__ ushort_t rne_bf16(float x) {
    unsigned u = __float_as_uint(x);
    return (ushort_t)((u + 0x7FFFu + ((u >> 16) & 1u)) >> 16);
}
__device__ __forceinline__ void split1(float x, ushort_t& h, ushort_t& l) {
    h = rne_bf16(x);
    float hf = __uint_as_float((unsigned)h << 16);
    l = rne_bf16(x - hf);
}

// ------------------------------ Prep ----------------------------------------
// blocks [0,512):    K split -> QK B-frag tiled layout (coalesced 16B writes)
// blocks [512,768):  V transpose-split -> PV B-frag tiled layout
// blocks [768,1024): mask bit-pack, thread-per-word
__global__ __launch_bounds__(256) void prep(
    const float* __restrict__ k, const float* __restrict__ v,
    const int* __restrict__ mask,
    ushort_t* __restrict__ khi, ushort_t* __restrict__ klo,
    ushort_t* __restrict__ vhi, ushort_t* __restrict__ vlo,
    unsigned* __restrict__ mw)
{
    __shared__ float Ls[64][65];
    const int tid = threadIdx.x;
    const int bx = blockIdx.x;
    if (bx < 512) {
        const int gid  = bx * 256 + tid;          // 0..131071
        const int bh   = gid >> 13;
        const int tile = (gid >> 7) & 63;
        const int ch   = (gid >> 6) & 1;
        const int lane = gid & 63;
        const int quad = lane >> 4, t15 = lane & 15;
        const float* src = k + ((size_t)bh * S_LEN + tile * 16 + t15) * D_DIM
                             + ch * 32 + quad * 8;
        float x[8];
        *(float4*)(x + 0) = *(const float4*)(src);
        *(float4*)(x + 4) = *(const float4*)(src + 4);
        short8 hv, lv;
        #pragma unroll
        for (int i = 0; i < 8; ++i) {
            ushort_t h, l;
            split1(x[i], h, l);
            hv[i] = (short)h; lv[i] = (short)l;
        }
        *(short8*)(khi + (size_t)gid * 8) = hv;
        *(short8*)(klo + (size_t)gid * 8) = lv;
    } else if (bx < 768) {
        const int bi = bx - 512;
        const int tt = bi & 15, bh = bi >> 4;
        const float* vb = v + ((size_t)bh * S_LEN + tt * 64) * D_DIM;
        #pragma unroll
        for (int p = 0; p < 4; ++p) {
            int idx = p * 1024 + tid * 4;
            int r = idx >> 6, c = idx & 63;
            float4 x = *(const float4*)(vb + r * 64 + c);
            Ls[r][c] = x.x; Ls[r][c+1] = x.y; Ls[r][c+2] = x.z; Ls[r][c+3] = x.w;
        }
        __syncthreads();
        const int d = tid >> 2, c0 = (tid & 3) * 16;
        ushort_t hi[16], lo[16];
        #pragma unroll
        for (int j = 0; j < 16; ++j) split1(Ls[c0 + j][d], hi[j], lo[j]);
        const int tb0 = tt * 8 + (c0 >> 3);
        const size_t o0 = (((size_t)bh * 128 + tb0) * 64 + d) * 8;
        const size_t o1 = (((size_t)bh * 128 + tb0 + 1) * 64 + d) * 8;
        *(short8*)(vhi + o0) = *(short8*)(hi);
        *(short8*)(vhi + o1) = *(short8*)(hi + 8);
        *(short8*)(vlo + o0) = *(short8*)(lo);
        *(short8*)(vlo + o1) = *(short8*)(lo + 8);
    } else {
        const int gid = (bx - 768) * 256 + tid;    // 0..65535
        const int row = gid >> 5, wd = gid & 31;   // row = b*1024+s
        const int4* mp = (const int4*)(mask + (size_t)row * 1024 + wd * 32);
        unsigned bits = 0;
        #pragma unroll
        for (int p = 0; p < 8; ++p) {
            int4 qv = mp[p];
            bits |= (qv.x != 0 ? 1u : 0u) << (p * 4 + 0);
            bits |= (qv.y != 0 ? 1u : 0u) << (p * 4 + 1);
            bits |= (qv.z != 0 ? 1u : 0u) << (p * 4 + 2);
            bits |= (qv.w != 0 ? 1u : 0u) << (p * 4 + 3);
        }
        mw[(size_t)row * 32 + wd] = bits;
    }
}

// ---------- K1: dp = (1/8) Q.K^T, MFMA, tiled K frags, coalesced stores ------
// grid (64 s-tiles, 16 bh), block 256 = 4 waves, no barriers.
// Wave w owns cols [w*256,(w+1)*256): 16 K-tiles in 4 sub-rounds of 4;
// after each sub-round, wave-private LDS transpose -> 256B-contig stores.
__global__ __launch_bounds__(256) void qk_mfma(
    const float* __restrict__ q,
    const ushort_t* __restrict__ khi, const ushort_t* __restrict__ klo,
    float* __restrict__ dp)
{
    __shared__ float Ls[4][16][68];       // 17.4 KB, per-wave private
    const int st = blockIdx.x, bh = blockIdx.y;
    const int s0 = st * 16;
    const int tid = threadIdx.x;
    const int wave = tid >> 6, lane = tid & 63;
    const int m = lane & 15, quad = lane >> 4;

    // A fragments: Q rows s0+m, fp32 load + in-register split (once per block)
    const float* qp = q + ((size_t)bh * S_LEN + s0 + m) * D_DIM + quad * 8;
    float qa[16];
    *(float4*)(qa + 0)  = *(const float4*)(qp + 0);
    *(float4*)(qa + 4)  = *(const float4*)(qp + 4);
    *(float4*)(qa + 8)  = *(const float4*)(qp + 32);
    *(float4*)(qa + 12) = *(const float4*)(qp + 36);
    short8 ahi0, alo0, ahi1, alo1;
    #pragma unroll
    for (int i = 0; i < 8; ++i) {
        ushort_t h, l;
        split1(qa[i], h, l);      ahi0[i] = (short)h; alo0[i] = (short)l;
        split1(qa[8 + i], h, l);  ahi1[i] = (short)h; alo1[i] = (short)l;
    }

    float* dpb = dp + ((size_t)bh * S_LEN + s0) * S_LEN;

    #pragma unroll
    for (int sub = 0; sub < 4; ++sub) {
        #pragma unroll
        for (int tt = 0; tt < 4; ++tt) {
            const int tile = wave * 16 + sub * 4 + tt;
            const size_t kb = (((size_t)bh * 64 + tile) * 128 + lane) * 8;
            short8 bhi0 = *(const short8*)(khi + kb);
            short8 blo0 = *(const short8*)(klo + kb);
            short8 bhi1 = *(const short8*)(khi + kb + 512);
            short8 blo1 = *(const short8*)(klo + kb + 512);
            f32x4 acc = {0.f, 0.f, 0.f, 0.f};
            acc = __builtin_amdgcn_mfma_f32_16x16x32_bf16(ahi0, bhi0, acc, 0, 0, 0);
            acc = __builtin_amdgcn_mfma_f32_16x16x32_bf16(ahi0, blo0, acc, 0, 0, 0);
            acc = __builtin_amdgcn_mfma_f32_16x16x32_bf16(alo0, bhi0, acc, 0, 0, 0);
            acc = __builtin_amdgcn_mfma_f32_16x16x32_bf16(ahi1, bhi1, acc, 0, 0, 0);
            acc = __builtin_amdgcn_mfma_f32_16x16x32_bf16(ahi1, blo1, acc, 0, 0, 0);
            acc = __builtin_amdgcn_mfma_f32_16x16x32_bf16(alo1, bhi1, acc, 0, 0, 0);
            #pragma unroll
            for (int r = 0; r < 4; ++r)
                Ls[wave][quad * 4 + r][tt * 16 + m] = acc[r] * 0.125f;
        }
        // wave-private transpose readback -> coalesced 256B-run stores
        const int cb = wave * 256 + sub * 64;
        #pragma unroll
        for (int p = 0; p < 4; ++p) {
            const int row = p * 4 + (lane >> 4);
            const int f4  = lane & 15;
            float4 val = *(const float4*)&Ls[wave][row][f4 * 4];
            *(float4*)&dpb[(size_t)row * S_LEN + cb + f4 * 4] = val;
        }
    }
}

// ---------- K2: conv+leaky+linear+mask+exp -> PV MFMA (direct global reads) --
// grid (64 s-tiles, 16 bh), block 512 = 8 waves. LDS ~40 KB -> 4 blocks/CU.
// Conv: thread (rh=tid>>8, cg=tid&255) -> rows rh*8..+7, cols cg*4..+3,
// two passes of 4 rows, 6-row register window straight from dp (L2/L3-hot).
// P = unnormalized exp bf16 in LDS; PV wave w: d0=(w&3)*16, t-half w>>2;
// 1/rowsum folded into epilogue.
#define PSTR 1048   // pP row stride in ushorts
__global__ __launch_bounds__(512) void conv_av(
    const float* __restrict__ dp, const unsigned* __restrict__ mw,
    const ushort_t* __restrict__ vhi, const ushort_t* __restrict__ vlo,
    const float* __restrict__ conv_w, const float* __restrict__ conv_b,
    const float* __restrict__ lin_w, const float* __restrict__ lin_b,
    float* __restrict__ out)
{
    __shared__ ushort_t pP[16 * PSTR];     // 33.5 KB
    __shared__ float oBuf[16][68];         // 4.4 KB
    __shared__ float lsPart[16][4];
    __shared__ unsigned mb[16][32];        // 2 KB

    const int st = blockIdx.x, bh = blockIdx.y;
    const int s0 = st * 16;
    const int b  = bh >> 3;
    const int tid = threadIdx.x;
    const int wave = tid >> 6, lane = tid & 63;
    const int m = lane & 15, quad = lane >> 4;

    {
        const int row = tid >> 5, wd = tid & 31;
        mb[row][wd] = mw[((size_t)b * S_LEN + s0 + row) * 32 + wd];
    }

    float w[36];
    #pragma unroll
    for (int i = 0; i < 36; ++i) w[i] = conv_w[i];
    float cb[4], lw[4];
    #pragma unroll
    for (int f = 0; f < 4; ++f) { cb[f] = conv_b[f]; lw[f] = lin_w[f]; }
    const float lb = lin_b[0];

    const int rh = tid >> 8, cg = tid & 255, c0 = cg * 4;
    const float* dpb = dp + (size_t)bh * S_LEN * S_LEN;
    __syncthreads();   // mb visible

    #pragma unroll
    for (int pass = 0; pass < 2; ++pass) {
        const int obase = rh * 8 + pass * 4;        // first of 4 output rows
        float rowv[6][6];
        #pragma unroll
        for (int jj = 0; jj < 6; ++jj) {
            const int ir = s0 + obase - 1 + jj;
            if (ir >= 0 && ir < S_LEN) {
                const float* rp = dpb + (size_t)ir * S_LEN + c0;
                f32x4 md = *(const f32x4*)rp;
                rowv[jj][0] = cg ? rp[-1] : 0.f;
                rowv[jj][1] = md.x; rowv[jj][2] = md.y;
                rowv[jj][3] = md.z; rowv[jj][4] = md.w;
                rowv[jj][5] = (cg < 255) ? rp[4] : 0.f;
            } else {
                #pragma unroll
                for (int i = 0; i < 6; ++i) rowv[jj][i] = 0.f;
            }
        }
        float ls[4];
        #pragma unroll
        for (int jo = 0; jo < 4; ++jo) {
            const int o = obase + jo;
            f32x2 pa = {lb, lb}, pb = {lb, lb};
            #pragma unroll
            for (int f = 0; f < 4; ++f) {
                f32x2 ca = {cb[f], cb[f]}, cbv = ca;
                #pragma unroll
                for (int dr = 0; dr < 3; ++dr) {
                    const float* vv = rowv[jo + dr];
                    #pragma unroll
                    for (int dc = 0; dc < 3; ++dc) {
                        const float wt = w[f * 9 + dr * 3 + dc];
                        f32x2 ia = {vv[dc],     vv[dc + 1]};
                        f32x2 ib = {vv[dc + 2], vv[dc + 3]};
                        ca  += wt * ia;
                        cbv += wt * ib;
                    }
                }
                f32x2 la  = {fmaxf(ca.x, 0.f)  + 0.01f * fminf(ca.x, 0.f),
                             fmaxf(ca.y, 0.f)  + 0.01f * fminf(ca.y, 0.f)};
                f32x2 lb2 = {fmaxf(cbv.x, 0.f) + 0.01f * fminf(cbv.x, 0.f),
                             fmaxf(cbv.y, 0.f) + 0.01f * fminf(cbv.y, 0.f)};
                pa += lw[f] * la;
                pb += lw[f] * lb2;
            }
            const unsigned word = mb[o][cg >> 3];
            const unsigned nib  = (word >> ((cg & 7) * 4)) & 0xFu;
            float pre[4] = {pa.x, pa.y, pb.x, pb.y};
            #pragma unroll
            for (int i = 0; i < 4; ++i)
                if (!((nib >> i) & 1u)) pre[i] = -1e30f;
            float pv[4];
            #pragma unroll
            for (int i = 0; i < 4; ++i) pv[i] = __expf(pre[i]);
            ls[jo] = (pv[0] + pv[1]) + (pv[2] + pv[3]);
            short4v hv = {(short)rne_bf16(pv[0]), (short)rne_bf16(pv[1]),
                          (short)rne_bf16(pv[2]), (short)rne_bf16(pv[3])};
            *(short4v*)&pP[o * PSTR + c0] = hv;
        }
        #pragma unroll
        for (int jo = 0; jo < 4; ++jo) {
            float t = ls[jo];
            #pragma unroll
            for (int off = 1; off < 64; off <<= 1) t += __shfl_xor(t, off);
            if (lane == 0) lsPart[obase + jo][wave & 3] = t;
        }
    }
    __syncthreads();

    // ---- PV: wave w -> d0=(w&3)*16, t-chunks (w>>2)*16 .. +15 --------------
    const int d0 = (wave & 3) * 16;
    const int th = wave >> 2;
    f32x4 O = {0.f, 0.f, 0.f, 0.f};
    #pragma unroll 4
    for (int i = 0; i < 16; ++i) {
        const int c = th * 16 + i;
        short8 ph = *(const short8*)&pP[m * PSTR + c * 32 + quad * 8];
        const size_t vb = (((size_t)bh * 128 + c * 4 + quad) * 64 + d0 + m) * 8;
        short8 vh = *(const short8*)(vhi + vb);
        short8 vl = *(const short8*)(vlo + vb);
        O = __builtin_amdgcn_mfma_f32_16x16x32_bf16(ph, vh, O, 0, 0, 0);
        O = __builtin_amdgcn_mfma_f32_16x16x32_bf16(ph, vl, O, 0, 0, 0);
    }
    if (wave < 4) {
        #pragma unroll
        for (int r = 0; r < 4; ++r) oBuf[quad * 4 + r][d0 + m] = O[r];
    }
    __syncthreads();
    if (wave >= 4) {
        #pragma unroll
        for (int r = 0; r < 4; ++r) {
            const int br = quad * 4 + r;
            const float lsum = (lsPart[br][0] + lsPart[br][1]) +
                               (lsPart[br][2] + lsPart[br][3]);
            out[((size_t)bh * S_LEN + s0 + br) * D_DIM + d0 + m] =
                (O[r] + oBuf[br][d0 + m]) / lsum;
        }
    }
}

extern "C" void kernel_launch(void* const* d_in, const int* in_sizes, int n_in,
                              void* d_out, int out_size, void* d_ws, size_t ws_size,
                              hipStream_t stream) {
    const float* q      = (const float*)d_in[0];
    const float* k      = (const float*)d_in[1];
    const float* v      = (const float*)d_in[2];
    const int*   mask   = (const int*)d_in[3];
    const float* conv_w = (const float*)d_in[4];
    const float* conv_b = (const float*)d_in[5];
    const float* lin_w  = (const float*)d_in[6];
    const float* lin_b  = (const float*)d_in[7];
    float* out = (float*)d_out;

    char* wsb = (char*)d_ws;
    const size_t MB = 1024 * 1024;
    ushort_t* khi = (ushort_t*)(wsb + 0 * MB);
    ushort_t* klo = (ushort_t*)(wsb + 2 * MB);
    ushort_t* vhi = (ushort_t*)(wsb + 4 * MB);
    ushort_t* vlo = (ushort_t*)(wsb + 6 * MB);
    unsigned* mw  = (unsigned*)(wsb + 8 * MB);
    float*    dp  = (float*)(wsb + 16 * MB);      // 64 MiB

    prep<<<dim3(1024), 256, 0, stream>>>(k, v, mask, khi, klo, vhi, vlo, mw);
    qk_mfma<<<dim3(64, NBH), 256, 0, stream>>>(q, khi, klo, dp);
    conv_av<<<dim3(64, NBH), 512, 0, stream>>>(
        dp, mw, vhi, vlo, conv_w, conv_b, lin_w, lin_b, out);
}